// Round 3
// baseline (523.960 us; speedup 1.0000x reference)
//
#include <hip/hip_runtime.h>
#include <math.h>

// ---------------------------------------------------------------------------
// StatePerturbationEncoder, R11: ONE fused kernel (prep + 4 layers), plain
// launch + hand-rolled grid barrier.
//  R9/R10 post-mortem: hipLaunchCooperativeKernel silently fails under the
//  harness's stream capture (absmax == max|ref| vs zero-fill, twice).
//  R11 keeps R10's structure exactly, but syncs via device-scope atomic
//  barrier. Co-residency guaranteed: launch_bounds(256,2) -> 2 blocks/CU,
//  grid 512 = 256 CUs x 2; bounded spin turns any deadlock into a visible
//  failure, not a hang.
//  * Activations never leave LDS (single 32KB panel P; BN-affine restage
//    is IN-PLACE on thread-exclusive swizzled slots).
//  * BN stats: 8-way sharded global atomicAdd (device scope = XCD-safe);
//    barrier fences: all-thread __threadfence (wbL2) before arrival,
//    AGENT-scope atomics, all-thread __threadfence (inv) after.
//  * GEMM core identical to R8 (proven): 64x256 tile, XOR-swizzled A panel,
//    1-deep K pipeline, B streamed from L2-hot Wt.
// ---------------------------------------------------------------------------

typedef __attribute__((ext_vector_type(8))) short short8;   // 8 x bf16
typedef __attribute__((ext_vector_type(4))) float floatx4;  // MFMA acc

#define DDIM 256
#define NBLK 512

struct Params {
    const int* ids;
    const float* table;
    const float* W[4];
    const float* b[4];
    const float* g[3];
    const float* be[3];
    unsigned short* Wt;    // ws: 4 * 65536 bf16
    float* stats;          // ws: 12288 f32 (3 layers x 8 shards x 512)
    unsigned int* barrier; // ws: 4 counters, memset to 0 each launch
    float* out;            // d_out f32
};

__device__ __forceinline__ unsigned short f2bf(float f) {
    union { float f; unsigned int u; } v; v.f = f;
    unsigned int r = v.u + 0x7fffu + ((v.u >> 16) & 1u);   // RNE
    return (unsigned short)(r >> 16);
}
__device__ __forceinline__ float bf2f(unsigned short u) {
    union { unsigned int i; float f; } v; v.i = ((unsigned int)u) << 16;
    return v.f;
}
__device__ __forceinline__ float gelu_fast(float x) {
    // tanh-approx GELU, branchless (validated: absmax 0.023 vs 0.076 thr)
    float z = 0.7978845608f * (x + 0.044715f * x * x * x);
    float e = __expf(2.0f * z);
    float th = 1.0f - 2.0f * __builtin_amdgcn_rcpf(1.0f + e);
    return 0.5f * x * (1.0f + th);
}

// ---------------------------------------------------------------------------
// Grid barrier: release-fence (per-wave vmcnt drain + L2 writeback) by ALL
// threads, AGENT-scope arrive+spin by thread 0, acquire-fence (cache inv)
// by ALL threads. Bounded spin: deadlock -> wrong answer, never a hang.
// ---------------------------------------------------------------------------
__device__ __forceinline__ void grid_barrier(unsigned int* cnt)
{
    __threadfence();                 // release: own stores -> coherence point
    __syncthreads();
    if (threadIdx.x == 0) {
        __hip_atomic_fetch_add(cnt, 1u, __ATOMIC_ACQ_REL,
                               __HIP_MEMORY_SCOPE_AGENT);
        int cap = 2000000;           // ~0.1-0.3 s worst case, then bail
        while (__hip_atomic_load(cnt, __ATOMIC_ACQUIRE,
                                 __HIP_MEMORY_SCOPE_AGENT) < (unsigned)NBLK) {
            __builtin_amdgcn_s_sleep(2);
            if (--cap == 0) break;
        }
    }
    __syncthreads();
    __threadfence();                 // acquire: invalidate stale L1/L2 lines
}

// ---------------------------------------------------------------------------
// One layer: (optional BN-affine in-place restage) -> GEMM -> GELU ->
// (act back into P + sharded stats | global f32 out).
// P layout: row r, granule g of 8 bf16 at slot (g ^ (r&7)) (conflict-free).
// ---------------------------------------------------------------------------
template<int GATHER, int AFFINE, int LAST>
__device__ __forceinline__ void layer_step(
    unsigned short* P, float* sc, float* sh,
    const Params& p,
    const unsigned short* Wt, const float* bias,
    const float* statsIn, const float* gma, const float* bta,
    float* statShards)
{
    const int tid  = threadIdx.x;
    const int blk  = blockIdx.x;
    const int wave = tid >> 6;
    const int lane = tid & 63;
    const int quad = lane >> 4;
    const int l15  = lane & 15;
    const int wn   = wave;
    const int row0 = blk * 64;

    if (AFFINE) {
        // thread t -> column t: finalize BN stats of the previous layer.
        // AGENT-scope relaxed loads: immune to stale XCD-L2 lines.
        float sum = 0.f, sq = 0.f;
#pragma unroll
        for (int s = 0; s < 8; ++s) {
            sum += __hip_atomic_load(&statsIn[s * 512 + tid],
                                     __ATOMIC_RELAXED, __HIP_MEMORY_SCOPE_AGENT);
            sq  += __hip_atomic_load(&statsIn[s * 512 + 256 + tid],
                                     __ATOMIC_RELAXED, __HIP_MEMORY_SCOPE_AGENT);
        }
        const float mu  = sum * (1.f / 32768.f);
        const float var = sq * (1.f / 32768.f) - mu * mu;
        const float scl = rsqrtf(var + 1e-5f) * gma[tid];
        sc[tid] = scl;
        sh[tid] = bta[tid] - mu * scl;
        __syncthreads();   // sc/sh visible before staging uses them
    }

    // ---- stage A panel (thread t: row t>>2, 64-col chunk (t&3)*64) ----
    {
        const int r  = tid >> 2;
        const int c0 = (tid & 3) * 64;
        if (GATHER) {
            const int src = p.ids[row0 + r];
            const float* tp = p.table + (size_t)src * DDIM + c0;
#pragma unroll
            for (int j = 0; j < 8; ++j) {
                float4 v0 = *(const float4*)(tp + j * 8);
                float4 v1 = *(const float4*)(tp + j * 8 + 4);
                union { unsigned short u[8]; uint4 v; } o;
                o.u[0]=f2bf(v0.x); o.u[1]=f2bf(v0.y); o.u[2]=f2bf(v0.z); o.u[3]=f2bf(v0.w);
                o.u[4]=f2bf(v1.x); o.u[5]=f2bf(v1.y); o.u[6]=f2bf(v1.z); o.u[7]=f2bf(v1.w);
                const int g = (tid & 3) * 8 + j;
                *(uint4*)(P + r * 256 + ((g ^ (r & 7)) << 3)) = o.v;
            }
        } else {
            // in-place BN-affine restage: thread-exclusive swizzled slots
            // (g^(r&7) only permutes low 3 bits -> stays in this thread's
            // own 8-granule range).
#pragma unroll
            for (int j = 0; j < 8; ++j) {
                const int g = (tid & 3) * 8 + j;
                unsigned short* slot = P + r * 256 + ((g ^ (r & 7)) << 3);
                union { unsigned short u[8]; uint4 v; } o;
                o.v = *(const uint4*)slot;
#pragma unroll
                for (int e = 0; e < 8; ++e) {
                    const int c = c0 + j * 8 + e;
                    o.u[e] = f2bf(fmaf(bf2f(o.u[e]), sc[c], sh[c]));
                }
                *(uint4*)slot = o.v;
            }
        }
    }

    float bias_v[4];
#pragma unroll
    for (int nt = 0; nt < 4; ++nt)
        bias_v[nt] = bias[wn * 64 + nt * 16 + l15];

    floatx4 acc[4][4];
#pragma unroll
    for (int i = 0; i < 4; ++i)
#pragma unroll
        for (int j = 0; j < 4; ++j)
            acc[i][j] = floatx4{0.f, 0.f, 0.f, 0.f};

    __syncthreads();   // A panel visible to all waves

    // ---- K loop: manual 1-deep pipeline; B from global (L2-hot), A LDS ----
    const unsigned short* wb = Wt + (size_t)(wn * 64 + l15) * DDIM + quad * 8;
    short8 bfr[4], bnx[4], af[4], anx[4];
    {
        const int agp = (quad ^ (l15 & 7)) * 8;               // kk = 0
#pragma unroll
        for (int nt = 0; nt < 4; ++nt)
            bfr[nt] = *(const short8*)(wb + (size_t)(nt * 16) * DDIM);
#pragma unroll
        for (int mt = 0; mt < 4; ++mt)
            af[mt] = *(const short8*)(P + (mt * 16 + l15) * 256 + agp);
    }
#pragma unroll
    for (int kk = 0; kk < 8; ++kk) {
        if (kk < 7) {
            const int agp = (((kk + 1) * 4 + quad) ^ (l15 & 7)) * 8;
#pragma unroll
            for (int nt = 0; nt < 4; ++nt)
                bnx[nt] = *(const short8*)(wb + (size_t)(nt * 16) * DDIM
                                           + (kk + 1) * 32);
#pragma unroll
            for (int mt = 0; mt < 4; ++mt)
                anx[mt] = *(const short8*)(P + (mt * 16 + l15) * 256 + agp);
        }
#pragma unroll
        for (int mt = 0; mt < 4; ++mt)
#pragma unroll
            for (int nt = 0; nt < 4; ++nt)
                acc[mt][nt] = __builtin_amdgcn_mfma_f32_16x16x32_bf16(
                    af[mt], bfr[nt], acc[mt][nt], 0, 0, 0);
#pragma unroll
        for (int x = 0; x < 4; ++x) { af[x] = anx[x]; bfr[x] = bnx[x]; }
    }

    if (!LAST) __syncthreads();   // all K-loop reads of P done before overwrite

    // ---- epilogue: bias + GELU; act -> P (swizzled) + sharded stats,
    //      or final layer -> global f32 out ----
    float s1[4] = {0.f, 0.f, 0.f, 0.f};
    float s2[4] = {0.f, 0.f, 0.f, 0.f};
#pragma unroll
    for (int mt = 0; mt < 4; ++mt) {
#pragma unroll
        for (int nt = 0; nt < 4; ++nt) {
            const int col = wn * 64 + nt * 16 + l15;         // C/D col=lane&15
#pragma unroll
            for (int i = 0; i < 4; ++i) {
                const int r = mt * 16 + quad * 4 + i;        // C/D row=quad*4+reg
                float y = gelu_fast(acc[mt][nt][i] + bias_v[nt]);
                if (LAST) {
                    p.out[(size_t)(row0 + r) * DDIM + col] = y;
                } else {
                    const int g = col >> 3;
                    P[r * 256 + ((g ^ (r & 7)) << 3) + (col & 7)] = f2bf(y);
                    s1[nt] += y; s2[nt] += y * y;
                }
            }
        }
    }
    if (!LAST) {
#pragma unroll
        for (int nt = 0; nt < 4; ++nt) {   // reduce the 4 quads (same column)
            s1[nt] += __shfl_xor(s1[nt], 16); s1[nt] += __shfl_xor(s1[nt], 32);
            s2[nt] += __shfl_xor(s2[nt], 16); s2[nt] += __shfl_xor(s2[nt], 32);
        }
        float* sb = statShards + (blk & 7) * 512;            // 8-way shard
        if (quad == 0) {
#pragma unroll
            for (int nt = 0; nt < 4; ++nt) {
                const int col = wn * 64 + nt * 16 + l15;
                atomicAdd(&sb[col],       s1[nt]);
                atomicAdd(&sb[256 + col], s2[nt]);
            }
        }
    }
}

// ---------------------------------------------------------------------------
// Fused kernel: phase0 (Wt transpose + stats zero) -> L1..L4, atomic-barrier
// separated. grid 512 x 256, 34KB static LDS, launch_bounds(256,2)
// -> exactly 2 blocks/CU co-resident.
// ---------------------------------------------------------------------------
__global__ __launch_bounds__(256, 2) void fused_enc(Params p)
{
    __shared__ alignas(16) unsigned short P[64 * 256];   // 32 KB panel
    __shared__ float sc[256], sh[256];                   // 2 KB

    const int tid = threadIdx.x, blk = blockIdx.x;

    // ---- phase 0: transpose+cast W -> Wt (bf16 [n][k]); zero stat shards.
    // block b handles rows 2*(b&127), +1 of W[b>>7]; coalesced 4B reads,
    // scattered 2B writes (512KB total, L2-absorbed).
    {
        const int j  = blk >> 7;
        const int n0 = (blk & 127) * 2;
        const float* W = p.W[j];
        unsigned short* dst = p.Wt + ((size_t)j << 16);
        dst[(size_t)tid * DDIM + n0]     = f2bf(W[(size_t)n0 * DDIM + tid]);
        dst[(size_t)tid * DDIM + n0 + 1] = f2bf(W[(size_t)(n0 + 1) * DDIM + tid]);
        if (blk < 12) {
            float* s = p.stats + blk * 1024;
            s[tid] = 0.f; s[tid + 256] = 0.f; s[tid + 512] = 0.f; s[tid + 768] = 0.f;
        }
    }
    grid_barrier(p.barrier + 0);

    layer_step<1, 0, 0>(P, sc, sh, p, p.Wt,          p.b[0],
                        nullptr,         nullptr, nullptr, p.stats);
    grid_barrier(p.barrier + 1);
    layer_step<0, 1, 0>(P, sc, sh, p, p.Wt + 65536,  p.b[1],
                        p.stats,         p.g[0],  p.be[0], p.stats + 4096);
    grid_barrier(p.barrier + 2);
    layer_step<0, 1, 0>(P, sc, sh, p, p.Wt + 131072, p.b[2],
                        p.stats + 4096,  p.g[1],  p.be[1], p.stats + 8192);
    grid_barrier(p.barrier + 3);
    layer_step<0, 1, 1>(P, sc, sh, p, p.Wt + 196608, p.b[3],
                        p.stats + 8192,  p.g[2],  p.be[2], nullptr);
}

// ---------------------------------------------------------------------------
extern "C" void kernel_launch(void* const* d_in, const int* in_sizes, int n_in,
                              void* d_out, int out_size, void* d_ws, size_t ws_size,
                              hipStream_t stream)
{
    Params pp;
    pp.ids   = (const int*)  d_in[0];
    pp.table = (const float*)d_in[1];
    pp.W[0] = (const float*)d_in[2];  pp.b[0] = (const float*)d_in[3];
    pp.W[1] = (const float*)d_in[4];  pp.b[1] = (const float*)d_in[5];
    pp.W[2] = (const float*)d_in[6];  pp.b[2] = (const float*)d_in[7];
    pp.W[3] = (const float*)d_in[8];  pp.b[3] = (const float*)d_in[9];
    pp.g[0] = (const float*)d_in[10]; pp.be[0] = (const float*)d_in[11];
    pp.g[1] = (const float*)d_in[12]; pp.be[1] = (const float*)d_in[13];
    pp.g[2] = (const float*)d_in[14]; pp.be[2] = (const float*)d_in[15];

    unsigned char* ws = (unsigned char*)d_ws;
    pp.Wt      = (unsigned short*)ws;                 // 512 KiB
    pp.stats   = (float*)(ws + (size_t)524288);       // 48 KiB
    pp.barrier = (unsigned int*)(ws + (size_t)589824);// 16 B
    pp.out     = (float*)d_out;

    // zero the 4 barrier counters (captured into the graph, replays fine)
    hipMemsetAsync(ws + (size_t)589824, 0, 16, stream);

    fused_enc<<<dim3(NBLK), dim3(256), 0, stream>>>(pp);
}

// Round 4
// 205.101 us; speedup vs baseline: 2.5546x; 2.5546x over previous
//
#include <hip/hip_runtime.h>
#include <math.h>

// ---------------------------------------------------------------------------
// StatePerturbationEncoder, R12: prep dispatch + ONE fused 4-layer kernel
// with featherweight grid barriers.
//  R11 post-mortem: 459us with VALUBusy 5% / Mfma 1.5% -> ~430us pure stall.
//  Cause: __threadfence() by ALL 2048 waves x8 (release+acquire x 4
//  barriers) emits buffer_wbl2/buffer_inv (L2 writeback/invalidate) per
//  wave: ~256 waves/XCD x ~200ns serialized ~= 50us per fence point x 8
//  ~= 400us. The acquire-side inv also evicted L2-hot Wt every layer.
//  Fences are unnecessary: cross-block data = BN stat shards only, written
//  by device-scope HW atomicAdd and read by AGENT-scope (sc1) atomic loads
//  -- both operate at the coherence point. Ordering comes free from
//  __syncthreads (compiler emits s_waitcnt vmcnt(0) before s_barrier).
//  Wt coherence: prep moved back to its own tiny dispatch (kernel boundary
//  flush, R8-proven).
//  Everything else identical to the PASSING R11 (absmax 0.0234).
// ---------------------------------------------------------------------------

typedef __attribute__((ext_vector_type(8))) short short8;   // 8 x bf16
typedef __attribute__((ext_vector_type(4))) float floatx4;  // MFMA acc

#define DDIM 256
#define NBLK 512

struct Params {
    const int* ids;
    const float* table;
    const float* b[4];
    const float* g[3];
    const float* be[3];
    const unsigned short* Wt;  // ws: 4 * 65536 bf16 (filled by prep)
    float* stats;              // ws: 12288 f32 (3 layers x 8 shards x 512)
    unsigned int* barrier;     // ws: 4 counters (zeroed by prep)
    float* out;                // d_out f32
};

__device__ __forceinline__ unsigned short f2bf(float f) {
    union { float f; unsigned int u; } v; v.f = f;
    unsigned int r = v.u + 0x7fffu + ((v.u >> 16) & 1u);   // RNE
    return (unsigned short)(r >> 16);
}
__device__ __forceinline__ float bf2f(unsigned short u) {
    union { unsigned int i; float f; } v; v.i = ((unsigned int)u) << 16;
    return v.f;
}
__device__ __forceinline__ float gelu_fast(float x) {
    // tanh-approx GELU, branchless (validated: absmax 0.023 vs 0.076 thr)
    float z = 0.7978845608f * (x + 0.044715f * x * x * x);
    float e = __expf(2.0f * z);
    float th = 1.0f - 2.0f * __builtin_amdgcn_rcpf(1.0f + e);
    return 0.5f * x * (1.0f + th);
}

// ---------------------------------------------------------------------------
// K0: transpose+cast all four W -> Wt (bf16 [n][k]); zero stat shards and
// barrier counters. grid 1024: block b handles row n=(b&255) of W[b>>8].
// ---------------------------------------------------------------------------
__global__ void prep_kernel(const float* __restrict__ W0,
                            const float* __restrict__ W1,
                            const float* __restrict__ W2,
                            const float* __restrict__ W3,
                            unsigned short* __restrict__ Wt,
                            float* __restrict__ stats,
                            unsigned int* __restrict__ barrier)
{
    const int t = threadIdx.x, b = blockIdx.x;
    const int j = b >> 8, n = b & 255;
    const float* W = (j == 0) ? W0 : (j == 1) ? W1 : (j == 2) ? W2 : W3;
    Wt[((size_t)j << 16) + (size_t)t * DDIM + n] = f2bf(W[(size_t)n * DDIM + t]);
    if (b < 12) {
        float* s = stats + b * 1024;
        s[t] = 0.f; s[t + 256] = 0.f; s[t + 512] = 0.f; s[t + 768] = 0.f;
    }
    if (b == 12 && t < 4) barrier[t] = 0u;
}

// ---------------------------------------------------------------------------
// Grid barrier, featherweight: __syncthreads drains each wave's vmcnt
// (stats atomics committed) + block sync; thread 0 does a RELAXED
// agent-scope arrive + bounded RELAXED spin (sc1 loads, no L2 inv).
// No buffer_wbl2 / buffer_inv anywhere. Bounded spin: deadlock -> wrong
// answer, never a hang.
// ---------------------------------------------------------------------------
__device__ __forceinline__ void grid_barrier(unsigned int* cnt)
{
    __syncthreads();   // s_waitcnt vmcnt(0) lgkmcnt(0) + s_barrier
    if (threadIdx.x == 0) {
        asm volatile("s_waitcnt vmcnt(0)" ::: "memory");
        __hip_atomic_fetch_add(cnt, 1u, __ATOMIC_RELAXED,
                               __HIP_MEMORY_SCOPE_AGENT);
        int cap = 20000000;
        while (__hip_atomic_load(cnt, __ATOMIC_RELAXED,
                                 __HIP_MEMORY_SCOPE_AGENT) < (unsigned)NBLK) {
            __builtin_amdgcn_s_sleep(1);
            if (--cap == 0) break;
        }
    }
    __syncthreads();
}

// ---------------------------------------------------------------------------
// One layer: (optional BN-affine in-place restage) -> GEMM -> GELU ->
// (act back into P + sharded stats | global f32 out).
// P layout: row r, granule g of 8 bf16 at slot (g ^ (r&7)) (conflict-free).
// ---------------------------------------------------------------------------
template<int GATHER, int AFFINE, int LAST>
__device__ __forceinline__ void layer_step(
    unsigned short* P, float* sc, float* sh,
    const Params& p,
    const unsigned short* Wt, const float* bias,
    const float* statsIn, const float* gma, const float* bta,
    float* statShards)
{
    const int tid  = threadIdx.x;
    const int blk  = blockIdx.x;
    const int wave = tid >> 6;
    const int lane = tid & 63;
    const int quad = lane >> 4;
    const int l15  = lane & 15;
    const int wn   = wave;
    const int row0 = blk * 64;

    if (AFFINE) {
        // thread t -> column t: finalize BN stats of the previous layer.
        // AGENT-scope (sc1) loads: read at coherence point, immune to
        // stale per-XCD L2 lines; no cache-wide invalidate needed.
        float sum = 0.f, sq = 0.f;
#pragma unroll
        for (int s = 0; s < 8; ++s) {
            sum += __hip_atomic_load(&statsIn[s * 512 + tid],
                                     __ATOMIC_RELAXED, __HIP_MEMORY_SCOPE_AGENT);
            sq  += __hip_atomic_load(&statsIn[s * 512 + 256 + tid],
                                     __ATOMIC_RELAXED, __HIP_MEMORY_SCOPE_AGENT);
        }
        const float mu  = sum * (1.f / 32768.f);
        const float var = sq * (1.f / 32768.f) - mu * mu;
        const float scl = rsqrtf(var + 1e-5f) * gma[tid];
        sc[tid] = scl;
        sh[tid] = bta[tid] - mu * scl;
        __syncthreads();   // sc/sh visible before staging uses them
    }

    // ---- stage A panel (thread t: row t>>2, 64-col chunk (t&3)*64) ----
    {
        const int r  = tid >> 2;
        const int c0 = (tid & 3) * 64;
        if (GATHER) {
            const int src = p.ids[row0 + r];
            const float* tp = p.table + (size_t)src * DDIM + c0;
#pragma unroll
            for (int j = 0; j < 8; ++j) {
                float4 v0 = *(const float4*)(tp + j * 8);
                float4 v1 = *(const float4*)(tp + j * 8 + 4);
                union { unsigned short u[8]; uint4 v; } o;
                o.u[0]=f2bf(v0.x); o.u[1]=f2bf(v0.y); o.u[2]=f2bf(v0.z); o.u[3]=f2bf(v0.w);
                o.u[4]=f2bf(v1.x); o.u[5]=f2bf(v1.y); o.u[6]=f2bf(v1.z); o.u[7]=f2bf(v1.w);
                const int g = (tid & 3) * 8 + j;
                *(uint4*)(P + r * 256 + ((g ^ (r & 7)) << 3)) = o.v;
            }
        } else {
            // in-place BN-affine restage: thread-exclusive swizzled slots
            // (g^(r&7) permutes only low 3 bits -> stays in this thread's
            // own 8-granule range).
#pragma unroll
            for (int j = 0; j < 8; ++j) {
                const int g = (tid & 3) * 8 + j;
                unsigned short* slot = P + r * 256 + ((g ^ (r & 7)) << 3);
                union { unsigned short u[8]; uint4 v; } o;
                o.v = *(const uint4*)slot;
#pragma unroll
                for (int e = 0; e < 8; ++e) {
                    const int c = c0 + j * 8 + e;
                    o.u[e] = f2bf(fmaf(bf2f(o.u[e]), sc[c], sh[c]));
                }
                *(uint4*)slot = o.v;
            }
        }
    }

    float bias_v[4];
#pragma unroll
    for (int nt = 0; nt < 4; ++nt)
        bias_v[nt] = bias[wn * 64 + nt * 16 + l15];

    floatx4 acc[4][4];
#pragma unroll
    for (int i = 0; i < 4; ++i)
#pragma unroll
        for (int j = 0; j < 4; ++j)
            acc[i][j] = floatx4{0.f, 0.f, 0.f, 0.f};

    __syncthreads();   // A panel visible to all waves

    // ---- K loop: manual 1-deep pipeline; B from global (L2-hot), A LDS ----
    const unsigned short* wb = Wt + (size_t)(wn * 64 + l15) * DDIM + quad * 8;
    short8 bfr[4], bnx[4], af[4], anx[4];
    {
        const int agp = (quad ^ (l15 & 7)) * 8;               // kk = 0
#pragma unroll
        for (int nt = 0; nt < 4; ++nt)
            bfr[nt] = *(const short8*)(wb + (size_t)(nt * 16) * DDIM);
#pragma unroll
        for (int mt = 0; mt < 4; ++mt)
            af[mt] = *(const short8*)(P + (mt * 16 + l15) * 256 + agp);
    }
#pragma unroll
    for (int kk = 0; kk < 8; ++kk) {
        if (kk < 7) {
            const int agp = (((kk + 1) * 4 + quad) ^ (l15 & 7)) * 8;
#pragma unroll
            for (int nt = 0; nt < 4; ++nt)
                bnx[nt] = *(const short8*)(wb + (size_t)(nt * 16) * DDIM
                                           + (kk + 1) * 32);
#pragma unroll
            for (int mt = 0; mt < 4; ++mt)
                anx[mt] = *(const short8*)(P + (mt * 16 + l15) * 256 + agp);
        }
#pragma unroll
        for (int mt = 0; mt < 4; ++mt)
#pragma unroll
            for (int nt = 0; nt < 4; ++nt)
                acc[mt][nt] = __builtin_amdgcn_mfma_f32_16x16x32_bf16(
                    af[mt], bfr[nt], acc[mt][nt], 0, 0, 0);
#pragma unroll
        for (int x = 0; x < 4; ++x) { af[x] = anx[x]; bfr[x] = bnx[x]; }
    }

    if (!LAST) __syncthreads();   // all K-loop reads of P done before overwrite

    // ---- epilogue: bias + GELU; act -> P (swizzled) + sharded stats,
    //      or final layer -> global f32 out ----
    float s1[4] = {0.f, 0.f, 0.f, 0.f};
    float s2[4] = {0.f, 0.f, 0.f, 0.f};
#pragma unroll
    for (int mt = 0; mt < 4; ++mt) {
#pragma unroll
        for (int nt = 0; nt < 4; ++nt) {
            const int col = wn * 64 + nt * 16 + l15;         // C/D col=lane&15
#pragma unroll
            for (int i = 0; i < 4; ++i) {
                const int r = mt * 16 + quad * 4 + i;        // C/D row=quad*4+reg
                float y = gelu_fast(acc[mt][nt][i] + bias_v[nt]);
                if (LAST) {
                    p.out[(size_t)(row0 + r) * DDIM + col] = y;
                } else {
                    const int g = col >> 3;
                    P[r * 256 + ((g ^ (r & 7)) << 3) + (col & 7)] = f2bf(y);
                    s1[nt] += y; s2[nt] += y * y;
                }
            }
        }
    }
    if (!LAST) {
#pragma unroll
        for (int nt = 0; nt < 4; ++nt) {   // reduce the 4 quads (same column)
            s1[nt] += __shfl_xor(s1[nt], 16); s1[nt] += __shfl_xor(s1[nt], 32);
            s2[nt] += __shfl_xor(s2[nt], 16); s2[nt] += __shfl_xor(s2[nt], 32);
        }
        float* sb = statShards + (blk & 7) * 512;            // 8-way shard
        if (quad == 0) {
#pragma unroll
            for (int nt = 0; nt < 4; ++nt) {
                const int col = wn * 64 + nt * 16 + l15;
                atomicAdd(&sb[col],       s1[nt]);
                atomicAdd(&sb[256 + col], s2[nt]);
            }
        }
    }
}

// ---------------------------------------------------------------------------
// Fused kernel: L1..L4, atomic-barrier separated. grid 512 x 256, 34KB
// static LDS, launch_bounds(256,2) -> exactly 2 blocks/CU co-resident.
// ---------------------------------------------------------------------------
__global__ __launch_bounds__(256, 2) void fused_enc(Params p)
{
    __shared__ alignas(16) unsigned short P[64 * 256];   // 32 KB panel
    __shared__ float sc[256], sh[256];                   // 2 KB

    layer_step<1, 0, 0>(P, sc, sh, p, p.Wt,          p.b[0],
                        nullptr,         nullptr, nullptr, p.stats);
    grid_barrier(p.barrier + 0);
    layer_step<0, 1, 0>(P, sc, sh, p, p.Wt + 65536,  p.b[1],
                        p.stats,         p.g[0],  p.be[0], p.stats + 4096);
    grid_barrier(p.barrier + 1);
    layer_step<0, 1, 0>(P, sc, sh, p, p.Wt + 131072, p.b[2],
                        p.stats + 4096,  p.g[1],  p.be[1], p.stats + 8192);
    grid_barrier(p.barrier + 2);
    layer_step<0, 1, 1>(P, sc, sh, p, p.Wt + 196608, p.b[3],
                        p.stats + 8192,  p.g[2],  p.be[2], nullptr);
}

// ---------------------------------------------------------------------------
extern "C" void kernel_launch(void* const* d_in, const int* in_sizes, int n_in,
                              void* d_out, int out_size, void* d_ws, size_t ws_size,
                              hipStream_t stream)
{
    const int*   ids   = (const int*)  d_in[0];
    const float* table = (const float*)d_in[1];
    const float* W1 = (const float*)d_in[2];
    const float* W2 = (const float*)d_in[4];
    const float* W3 = (const float*)d_in[6];
    const float* W4 = (const float*)d_in[8];

    Params pp;
    pp.ids   = ids;
    pp.table = table;
    pp.b[0] = (const float*)d_in[3];
    pp.b[1] = (const float*)d_in[5];
    pp.b[2] = (const float*)d_in[7];
    pp.b[3] = (const float*)d_in[9];
    pp.g[0] = (const float*)d_in[10]; pp.be[0] = (const float*)d_in[11];
    pp.g[1] = (const float*)d_in[12]; pp.be[1] = (const float*)d_in[13];
    pp.g[2] = (const float*)d_in[14]; pp.be[2] = (const float*)d_in[15];

    unsigned char* ws = (unsigned char*)d_ws;
    unsigned short* Wt = (unsigned short*)ws;             // 512 KiB
    float* stats       = (float*)(ws + (size_t)524288);   // 48 KiB
    unsigned int* bar  = (unsigned int*)(ws + (size_t)589824); // 16 B

    pp.Wt      = Wt;
    pp.stats   = stats;
    pp.barrier = bar;
    pp.out     = (float*)d_out;

    prep_kernel<<<1024, 256, 0, stream>>>(W1, W2, W3, W4, Wt, stats, bar);
    fused_enc<<<dim3(NBLK), dim3(256), 0, stream>>>(pp);
}

// Round 5
// 196.875 us; speedup vs baseline: 2.6614x; 1.0418x over previous
//
#include <hip/hip_runtime.h>
#include <math.h>

// ---------------------------------------------------------------------------
// StatePerturbationEncoder, R13: prep + ONE fused 4-layer kernel, 8 waves.
//  R12 post-mortem: fence-free barrier worked (459->113.7us, passes). The
//  remaining ~85us of fused_enc is latency stall at 2 waves/SIMD
//  (VALUBusy 19%, Mfma 5.7%, Occ 22%): staging gather latency, K-loop
//  B-load latency and the 64-GELU-per-thread epilogue chain are all
//  exposed.
//  R13:
//   * 512 threads/block (8 waves), same 64x256 block tile and 512-block
//     grid (barrier residency invariant). Wave owns 32 cols -> acc 4x2,
//     per-thread staging/epilogue work halves, 4 waves/SIMD hides latency.
//     __launch_bounds__(512,4) -> VGPR<=128 -> 2 blocks/CU co-resident.
//   * prep flipped to scattered-READ + coalesced-WRITE (2B scattered
//     writes were the cost; scattered column reads are L2-absorbed).
//  Math identical to R12 (absmax 0.0234 expected unchanged).
// ---------------------------------------------------------------------------

typedef __attribute__((ext_vector_type(8))) short short8;   // 8 x bf16
typedef __attribute__((ext_vector_type(4))) float floatx4;  // MFMA acc

#define DDIM 256
#define NBLK 512

struct Params {
    const int* ids;
    const float* table;
    const float* b[4];
    const float* g[3];
    const float* be[3];
    const unsigned short* Wt;  // ws: 4 * 65536 bf16 (filled by prep)
    float* stats;              // ws: 12288 f32 (3 layers x 8 shards x 512)
    unsigned int* barrier;     // ws: 4 counters (zeroed by prep)
    float* out;                // d_out f32
};

__device__ __forceinline__ unsigned short f2bf(float f) {
    union { float f; unsigned int u; } v; v.f = f;
    unsigned int r = v.u + 0x7fffu + ((v.u >> 16) & 1u);   // RNE
    return (unsigned short)(r >> 16);
}
__device__ __forceinline__ float bf2f(unsigned short u) {
    union { unsigned int i; float f; } v; v.i = ((unsigned int)u) << 16;
    return v.f;
}
__device__ __forceinline__ float gelu_fast(float x) {
    // tanh-approx GELU, branchless (validated: absmax 0.023 vs 0.076 thr)
    float z = 0.7978845608f * (x + 0.044715f * x * x * x);
    float e = __expf(2.0f * z);
    float th = 1.0f - 2.0f * __builtin_amdgcn_rcpf(1.0f + e);
    return 0.5f * x * (1.0f + th);
}

// ---------------------------------------------------------------------------
// K0: transpose+cast all four W -> Wt (bf16 [n][k]); zero stat shards and
// barrier counters. Block b handles OUTPUT row n=(b&255) of W[b>>8]:
// coalesced 2B writes (512B/wave-row); scattered 4B column reads are
// L2-absorbed (each 64B line of W is shared by 16 consecutive blocks).
// ---------------------------------------------------------------------------
__global__ void prep_kernel(const float* __restrict__ W0,
                            const float* __restrict__ W1,
                            const float* __restrict__ W2,
                            const float* __restrict__ W3,
                            unsigned short* __restrict__ Wt,
                            float* __restrict__ stats,
                            unsigned int* __restrict__ barrier)
{
    const int t = threadIdx.x, b = blockIdx.x;
    const int j = b >> 8, n = b & 255;
    const float* W = (j == 0) ? W0 : (j == 1) ? W1 : (j == 2) ? W2 : W3;
    Wt[((size_t)j << 16) + (size_t)n * DDIM + t] = f2bf(W[(size_t)t * DDIM + n]);
    if (b < 12) {
        float* s = stats + b * 1024;
        s[t] = 0.f; s[t + 256] = 0.f; s[t + 512] = 0.f; s[t + 768] = 0.f;
    }
    if (b == 12 && t < 4) barrier[t] = 0u;
}

// ---------------------------------------------------------------------------
// Grid barrier, featherweight (R12-proven): __syncthreads drains each
// wave's vmcnt (stats atomics committed) + block sync; thread 0 does a
// RELAXED agent-scope arrive + bounded RELAXED spin (sc1, no L2 wb/inv).
// Bounded spin: deadlock -> wrong answer, never a hang.
// ---------------------------------------------------------------------------
__device__ __forceinline__ void grid_barrier(unsigned int* cnt)
{
    __syncthreads();
    if (threadIdx.x == 0) {
        asm volatile("s_waitcnt vmcnt(0)" ::: "memory");
        __hip_atomic_fetch_add(cnt, 1u, __ATOMIC_RELAXED,
                               __HIP_MEMORY_SCOPE_AGENT);
        int cap = 20000000;
        while (__hip_atomic_load(cnt, __ATOMIC_RELAXED,
                                 __HIP_MEMORY_SCOPE_AGENT) < (unsigned)NBLK) {
            __builtin_amdgcn_s_sleep(1);
            if (--cap == 0) break;
        }
    }
    __syncthreads();
}

// ---------------------------------------------------------------------------
// One layer, 8-wave version. Block tile 64 rows x 256 cols; wave wn owns
// cols wn*32..+31 (acc 4x2 of 16x16x32 MFMAs).
// P layout: row r, granule g (8 bf16) at slot g^(r&7) (conflict-free).
// ---------------------------------------------------------------------------
template<int GATHER, int AFFINE, int LAST>
__device__ __forceinline__ void layer_step(
    unsigned short* P, float* sc, float* sh,
    const Params& p,
    const unsigned short* Wt, const float* bias,
    const float* statsIn, const float* gma, const float* bta,
    float* statShards)
{
    const int tid  = threadIdx.x;          // 0..511
    const int blk  = blockIdx.x;
    const int wave = tid >> 6;             // 0..7
    const int lane = tid & 63;
    const int quad = lane >> 4;
    const int l15  = lane & 15;
    const int row0 = blk * 64;

    if (AFFINE) {
        // threads 0..255 -> column t: finalize BN stats of prev layer.
        // AGENT-scope (sc1) loads read at the coherence point (XCD-safe).
        if (tid < 256) {
            float sum = 0.f, sq = 0.f;
#pragma unroll
            for (int s = 0; s < 8; ++s) {
                sum += __hip_atomic_load(&statsIn[s * 512 + tid],
                                         __ATOMIC_RELAXED, __HIP_MEMORY_SCOPE_AGENT);
                sq  += __hip_atomic_load(&statsIn[s * 512 + 256 + tid],
                                         __ATOMIC_RELAXED, __HIP_MEMORY_SCOPE_AGENT);
            }
            const float mu  = sum * (1.f / 32768.f);
            const float var = sq * (1.f / 32768.f) - mu * mu;
            const float scl = rsqrtf(var + 1e-5f) * gma[tid];
            sc[tid] = scl;
            sh[tid] = bta[tid] - mu * scl;
        }
        __syncthreads();   // sc/sh visible before staging uses them
    }

    // ---- stage A panel (thread t: row t>>3, granules (t&7)*4 .. +3) ----
    {
        const int r     = tid >> 3;
        const int gbase = (tid & 7) * 4;
        if (GATHER) {
            const int src = p.ids[row0 + r];
            const float* tp = p.table + (size_t)src * DDIM + gbase * 8;
#pragma unroll
            for (int j = 0; j < 4; ++j) {
                float4 v0 = *(const float4*)(tp + j * 8);
                float4 v1 = *(const float4*)(tp + j * 8 + 4);
                union { unsigned short u[8]; uint4 v; } o;
                o.u[0]=f2bf(v0.x); o.u[1]=f2bf(v0.y); o.u[2]=f2bf(v0.z); o.u[3]=f2bf(v0.w);
                o.u[4]=f2bf(v1.x); o.u[5]=f2bf(v1.y); o.u[6]=f2bf(v1.z); o.u[7]=f2bf(v1.w);
                const int g = gbase + j;
                *(uint4*)(P + r * 256 + ((g ^ (r & 7)) << 3)) = o.v;
            }
        } else {
            // in-place BN-affine restage. Thread enumerates its own DATA
            // granules g; slot map g->g^(r&7) is a bijection per row, so
            // slots are touched by exactly one thread (read-mod-write safe).
#pragma unroll
            for (int j = 0; j < 4; ++j) {
                const int g = gbase + j;
                unsigned short* slot = P + r * 256 + ((g ^ (r & 7)) << 3);
                union { unsigned short u[8]; uint4 v; } o;
                o.v = *(const uint4*)slot;
#pragma unroll
                for (int e = 0; e < 8; ++e) {
                    const int c = g * 8 + e;
                    o.u[e] = f2bf(fmaf(bf2f(o.u[e]), sc[c], sh[c]));
                }
                *(uint4*)slot = o.v;
            }
        }
    }

    float bias_v[2];
#pragma unroll
    for (int nt = 0; nt < 2; ++nt)
        bias_v[nt] = bias[wave * 32 + nt * 16 + l15];

    floatx4 acc[4][2];
#pragma unroll
    for (int i = 0; i < 4; ++i)
#pragma unroll
        for (int j = 0; j < 2; ++j)
            acc[i][j] = floatx4{0.f, 0.f, 0.f, 0.f};

    __syncthreads();   // A panel visible to all waves

    // ---- K loop: manual 1-deep pipeline; B from global (L2-hot), A LDS ----
    const unsigned short* wb = Wt + (size_t)(wave * 32 + l15) * DDIM + quad * 8;
    short8 bfr[2], bnx[2], af[4], anx[4];
    {
        const int agp = (quad ^ (l15 & 7)) * 8;               // kk = 0
#pragma unroll
        for (int nt = 0; nt < 2; ++nt)
            bfr[nt] = *(const short8*)(wb + (size_t)(nt * 16) * DDIM);
#pragma unroll
        for (int mt = 0; mt < 4; ++mt)
            af[mt] = *(const short8*)(P + (mt * 16 + l15) * 256 + agp);
    }
#pragma unroll
    for (int kk = 0; kk < 8; ++kk) {
        if (kk < 7) {
            const int agp = (((kk + 1) * 4 + quad) ^ (l15 & 7)) * 8;
#pragma unroll
            for (int nt = 0; nt < 2; ++nt)
                bnx[nt] = *(const short8*)(wb + (size_t)(nt * 16) * DDIM
                                           + (kk + 1) * 32);
#pragma unroll
            for (int mt = 0; mt < 4; ++mt)
                anx[mt] = *(const short8*)(P + (mt * 16 + l15) * 256 + agp);
        }
#pragma unroll
        for (int mt = 0; mt < 4; ++mt)
#pragma unroll
            for (int nt = 0; nt < 2; ++nt)
                acc[mt][nt] = __builtin_amdgcn_mfma_f32_16x16x32_bf16(
                    af[mt], bfr[nt], acc[mt][nt], 0, 0, 0);
#pragma unroll
        for (int x = 0; x < 4; ++x) af[x] = anx[x];
#pragma unroll
        for (int x = 0; x < 2; ++x) bfr[x] = bnx[x];
    }

    if (!LAST) __syncthreads();   // all K-loop reads of P done before overwrite

    // ---- epilogue: bias + GELU; act -> P (swizzled) + sharded stats,
    //      or final layer -> global f32 out ----
    float s1[2] = {0.f, 0.f};
    float s2[2] = {0.f, 0.f};
#pragma unroll
    for (int mt = 0; mt < 4; ++mt) {
#pragma unroll
        for (int nt = 0; nt < 2; ++nt) {
            const int col = wave * 32 + nt * 16 + l15;       // C/D col=lane&15
#pragma unroll
            for (int i = 0; i < 4; ++i) {
                const int r = mt * 16 + quad * 4 + i;        // C/D row=quad*4+reg
                float y = gelu_fast(acc[mt][nt][i] + bias_v[nt]);
                if (LAST) {
                    p.out[(size_t)(row0 + r) * DDIM + col] = y;
                } else {
                    const int g = col >> 3;
                    P[r * 256 + ((g ^ (r & 7)) << 3) + (col & 7)] = f2bf(y);
                    s1[nt] += y; s2[nt] += y * y;
                }
            }
        }
    }
    if (!LAST) {
#pragma unroll
        for (int nt = 0; nt < 2; ++nt) {   // reduce the 4 quads (same column)
            s1[nt] += __shfl_xor(s1[nt], 16); s1[nt] += __shfl_xor(s1[nt], 32);
            s2[nt] += __shfl_xor(s2[nt], 16); s2[nt] += __shfl_xor(s2[nt], 32);
        }
        float* sb = statShards + (blk & 7) * 512;            // 8-way shard
        if (quad == 0) {
#pragma unroll
            for (int nt = 0; nt < 2; ++nt) {
                const int col = wave * 32 + nt * 16 + l15;
                atomicAdd(&sb[col],       s1[nt]);
                atomicAdd(&sb[256 + col], s2[nt]);
            }
        }
    }
}

// ---------------------------------------------------------------------------
// Fused kernel: L1..L4, atomic-barrier separated. grid 512 x 512thr, 34KB
// static LDS, launch_bounds(512,4) -> VGPR<=128 -> 2 blocks/CU resident.
// ---------------------------------------------------------------------------
__global__ __launch_bounds__(512, 4) void fused_enc(Params p)
{
    __shared__ alignas(16) unsigned short P[64 * 256];   // 32 KB panel
    __shared__ float sc[256], sh[256];                   // 2 KB

    layer_step<1, 0, 0>(P, sc, sh, p, p.Wt,          p.b[0],
                        nullptr,         nullptr, nullptr, p.stats);
    grid_barrier(p.barrier + 0);
    layer_step<0, 1, 0>(P, sc, sh, p, p.Wt + 65536,  p.b[1],
                        p.stats,         p.g[0],  p.be[0], p.stats + 4096);
    grid_barrier(p.barrier + 1);
    layer_step<0, 1, 0>(P, sc, sh, p, p.Wt + 131072, p.b[2],
                        p.stats + 4096,  p.g[1],  p.be[1], p.stats + 8192);
    grid_barrier(p.barrier + 2);
    layer_step<0, 1, 1>(P, sc, sh, p, p.Wt + 196608, p.b[3],
                        p.stats + 8192,  p.g[2],  p.be[2], nullptr);
}

// ---------------------------------------------------------------------------
extern "C" void kernel_launch(void* const* d_in, const int* in_sizes, int n_in,
                              void* d_out, int out_size, void* d_ws, size_t ws_size,
                              hipStream_t stream)
{
    const float* W1 = (const float*)d_in[2];
    const float* W2 = (const float*)d_in[4];
    const float* W3 = (const float*)d_in[6];
    const float* W4 = (const float*)d_in[8];

    Params pp;
    pp.ids   = (const int*)  d_in[0];
    pp.table = (const float*)d_in[1];
    pp.b[0] = (const float*)d_in[3];
    pp.b[1] = (const float*)d_in[5];
    pp.b[2] = (const float*)d_in[7];
    pp.b[3] = (const float*)d_in[9];
    pp.g[0] = (const float*)d_in[10]; pp.be[0] = (const float*)d_in[11];
    pp.g[1] = (const float*)d_in[12]; pp.be[1] = (const float*)d_in[13];
    pp.g[2] = (const float*)d_in[14]; pp.be[2] = (const float*)d_in[15];

    unsigned char* ws = (unsigned char*)d_ws;
    unsigned short* Wt = (unsigned short*)ws;             // 512 KiB
    float* stats       = (float*)(ws + (size_t)524288);   // 48 KiB
    unsigned int* bar  = (unsigned int*)(ws + (size_t)589824); // 16 B

    pp.Wt      = Wt;
    pp.stats   = stats;
    pp.barrier = bar;
    pp.out     = (float*)d_out;

    prep_kernel<<<1024, 256, 0, stream>>>(W1, W2, W3, W4, Wt, stats, bar);
    fused_enc<<<dim3(NBLK), dim3(512), 0, stream>>>(pp);
}

// Round 6
// 175.083 us; speedup vs baseline: 2.9926x; 1.1245x over previous
//
#include <hip/hip_runtime.h>
#include <math.h>

// ---------------------------------------------------------------------------
// StatePerturbationEncoder, R14: R13 + decontended grid barrier.
//  R13 post-mortem: occupancy 22->43% but time 113.7->107us; VALUBusy flat.
//  => ~100us TLP-invariant serial component. Theory: poll storm. 512
//  thread-0 spinners issue sc1 loads every ~200ns against the SAME line
//  that also receives the 512 arrival fetch_adds; RMWs queue behind the
//  read storm -> arrivals+detection serialize (~25us/barrier x 3).
//  R14 barrier: arrive-counter (RMW-only line) SPLIT from release-flag
//  (read-only line, set by the last arriver); pollers back off with
//  s_sleep(8) (~0.2us grain). Per-phase counter+flag pairs zeroed by prep.
//  Everything else byte-identical to the passing R13 (absmax 0.0234).
// ---------------------------------------------------------------------------

typedef __attribute__((ext_vector_type(8))) short short8;   // 8 x bf16
typedef __attribute__((ext_vector_type(4))) float floatx4;  // MFMA acc

#define DDIM 256
#define NBLK 512

struct Params {
    const int* ids;
    const float* table;
    const float* b[4];
    const float* g[3];
    const float* be[3];
    const unsigned short* Wt;  // ws: 4 * 65536 bf16 (filled by prep)
    float* stats;              // ws: 12288 f32 (3 layers x 8 shards x 512)
    unsigned int* barrier;     // ws: 2KB region (cnt lines + flag lines)
    float* out;                // d_out f32
};

__device__ __forceinline__ unsigned short f2bf(float f) {
    union { float f; unsigned int u; } v; v.f = f;
    unsigned int r = v.u + 0x7fffu + ((v.u >> 16) & 1u);   // RNE
    return (unsigned short)(r >> 16);
}
__device__ __forceinline__ float bf2f(unsigned short u) {
    union { unsigned int i; float f; } v; v.i = ((unsigned int)u) << 16;
    return v.f;
}
__device__ __forceinline__ float gelu_fast(float x) {
    // tanh-approx GELU, branchless (validated: absmax 0.023 vs 0.076 thr)
    float z = 0.7978845608f * (x + 0.044715f * x * x * x);
    float e = __expf(2.0f * z);
    float th = 1.0f - 2.0f * __builtin_amdgcn_rcpf(1.0f + e);
    return 0.5f * x * (1.0f + th);
}

// ---------------------------------------------------------------------------
// K0: transpose+cast all four W -> Wt (bf16 [n][k]); zero stat shards and
// the barrier region. Block b handles OUTPUT row n=(b&255) of W[b>>8]:
// coalesced 2B writes; scattered 4B column reads are L2-absorbed.
// ---------------------------------------------------------------------------
__global__ void prep_kernel(const float* __restrict__ W0,
                            const float* __restrict__ W1,
                            const float* __restrict__ W2,
                            const float* __restrict__ W3,
                            unsigned short* __restrict__ Wt,
                            float* __restrict__ stats,
                            unsigned int* __restrict__ barrier)
{
    const int t = threadIdx.x, b = blockIdx.x;
    const int j = b >> 8, n = b & 255;
    const float* W = (j == 0) ? W0 : (j == 1) ? W1 : (j == 2) ? W2 : W3;
    Wt[((size_t)j << 16) + (size_t)n * DDIM + t] = f2bf(W[(size_t)t * DDIM + n]);
    if (b < 12) {
        float* s = stats + b * 1024;
        s[t] = 0.f; s[t + 256] = 0.f; s[t + 512] = 0.f; s[t + 768] = 0.f;
    }
    if (b == 12) { barrier[t] = 0u; barrier[t + 256] = 0u; }  // 2KB region
}

// ---------------------------------------------------------------------------
// Grid barrier, decontended: __syncthreads drains each wave's vmcnt (stats
// atomics committed); thread 0 arrives on a RMW-only counter line; the
// LAST arriver sets a flag on a SEPARATE line; others poll the read-only
// flag with s_sleep(8) backoff. No L2 wb/inv anywhere. Bounded spin:
// deadlock -> wrong answer, never a hang.
// cnt = barrier + phase*16 (64B apart); flag = barrier + 256 + phase*16.
// ---------------------------------------------------------------------------
__device__ __forceinline__ void grid_barrier(unsigned int* base, int phase)
{
    unsigned int* cnt  = base + phase * 16;
    unsigned int* flag = base + 256 + phase * 16;
    __syncthreads();
    if (threadIdx.x == 0) {
        asm volatile("s_waitcnt vmcnt(0)" ::: "memory");
        unsigned int old = __hip_atomic_fetch_add(cnt, 1u, __ATOMIC_RELAXED,
                                                  __HIP_MEMORY_SCOPE_AGENT);
        if (old == (unsigned)(NBLK - 1)) {
            __hip_atomic_store(flag, 1u, __ATOMIC_RELAXED,
                               __HIP_MEMORY_SCOPE_AGENT);
        } else {
            int cap = 2000000;
            while (!__hip_atomic_load(flag, __ATOMIC_RELAXED,
                                      __HIP_MEMORY_SCOPE_AGENT)) {
                __builtin_amdgcn_s_sleep(8);
                if (--cap == 0) break;
            }
        }
    }
    __syncthreads();
}

// ---------------------------------------------------------------------------
// One layer, 8-wave version. Block tile 64 rows x 256 cols; wave wn owns
// cols wn*32..+31 (acc 4x2 of 16x16x32 MFMAs).
// P layout: row r, granule g (8 bf16) at slot g^(r&7) (conflict-free).
// ---------------------------------------------------------------------------
template<int GATHER, int AFFINE, int LAST>
__device__ __forceinline__ void layer_step(
    unsigned short* P, float* sc, float* sh,
    const Params& p,
    const unsigned short* Wt, const float* bias,
    const float* statsIn, const float* gma, const float* bta,
    float* statShards)
{
    const int tid  = threadIdx.x;          // 0..511
    const int blk  = blockIdx.x;
    const int wave = tid >> 6;             // 0..7
    const int lane = tid & 63;
    const int quad = lane >> 4;
    const int l15  = lane & 15;
    const int row0 = blk * 64;

    if (AFFINE) {
        // threads 0..255 -> column t: finalize BN stats of prev layer.
        // AGENT-scope (sc1) loads read at the coherence point (XCD-safe).
        if (tid < 256) {
            float sum = 0.f, sq = 0.f;
#pragma unroll
            for (int s = 0; s < 8; ++s) {
                sum += __hip_atomic_load(&statsIn[s * 512 + tid],
                                         __ATOMIC_RELAXED, __HIP_MEMORY_SCOPE_AGENT);
                sq  += __hip_atomic_load(&statsIn[s * 512 + 256 + tid],
                                         __ATOMIC_RELAXED, __HIP_MEMORY_SCOPE_AGENT);
            }
            const float mu  = sum * (1.f / 32768.f);
            const float var = sq * (1.f / 32768.f) - mu * mu;
            const float scl = rsqrtf(var + 1e-5f) * gma[tid];
            sc[tid] = scl;
            sh[tid] = bta[tid] - mu * scl;
        }
        __syncthreads();   // sc/sh visible before staging uses them
    }

    // ---- stage A panel (thread t: row t>>3, granules (t&7)*4 .. +3) ----
    {
        const int r     = tid >> 3;
        const int gbase = (tid & 7) * 4;
        if (GATHER) {
            const int src = p.ids[row0 + r];
            const float* tp = p.table + (size_t)src * DDIM + gbase * 8;
#pragma unroll
            for (int j = 0; j < 4; ++j) {
                float4 v0 = *(const float4*)(tp + j * 8);
                float4 v1 = *(const float4*)(tp + j * 8 + 4);
                union { unsigned short u[8]; uint4 v; } o;
                o.u[0]=f2bf(v0.x); o.u[1]=f2bf(v0.y); o.u[2]=f2bf(v0.z); o.u[3]=f2bf(v0.w);
                o.u[4]=f2bf(v1.x); o.u[5]=f2bf(v1.y); o.u[6]=f2bf(v1.z); o.u[7]=f2bf(v1.w);
                const int g = gbase + j;
                *(uint4*)(P + r * 256 + ((g ^ (r & 7)) << 3)) = o.v;
            }
        } else {
            // in-place BN-affine restage. Thread enumerates its own DATA
            // granules g; slot map g->g^(r&7) is a bijection per row, so
            // slots are touched by exactly one thread (read-mod-write safe).
#pragma unroll
            for (int j = 0; j < 4; ++j) {
                const int g = gbase + j;
                unsigned short* slot = P + r * 256 + ((g ^ (r & 7)) << 3);
                union { unsigned short u[8]; uint4 v; } o;
                o.v = *(const uint4*)slot;
#pragma unroll
                for (int e = 0; e < 8; ++e) {
                    const int c = g * 8 + e;
                    o.u[e] = f2bf(fmaf(bf2f(o.u[e]), sc[c], sh[c]));
                }
                *(uint4*)slot = o.v;
            }
        }
    }

    float bias_v[2];
#pragma unroll
    for (int nt = 0; nt < 2; ++nt)
        bias_v[nt] = bias[wave * 32 + nt * 16 + l15];

    floatx4 acc[4][2];
#pragma unroll
    for (int i = 0; i < 4; ++i)
#pragma unroll
        for (int j = 0; j < 2; ++j)
            acc[i][j] = floatx4{0.f, 0.f, 0.f, 0.f};

    __syncthreads();   // A panel visible to all waves

    // ---- K loop: manual 1-deep pipeline; B from global (L2-hot), A LDS ----
    const unsigned short* wb = Wt + (size_t)(wave * 32 + l15) * DDIM + quad * 8;
    short8 bfr[2], bnx[2], af[4], anx[4];
    {
        const int agp = (quad ^ (l15 & 7)) * 8;               // kk = 0
#pragma unroll
        for (int nt = 0; nt < 2; ++nt)
            bfr[nt] = *(const short8*)(wb + (size_t)(nt * 16) * DDIM);
#pragma unroll
        for (int mt = 0; mt < 4; ++mt)
            af[mt] = *(const short8*)(P + (mt * 16 + l15) * 256 + agp);
    }
#pragma unroll
    for (int kk = 0; kk < 8; ++kk) {
        if (kk < 7) {
            const int agp = (((kk + 1) * 4 + quad) ^ (l15 & 7)) * 8;
#pragma unroll
            for (int nt = 0; nt < 2; ++nt)
                bnx[nt] = *(const short8*)(wb + (size_t)(nt * 16) * DDIM
                                           + (kk + 1) * 32);
#pragma unroll
            for (int mt = 0; mt < 4; ++mt)
                anx[mt] = *(const short8*)(P + (mt * 16 + l15) * 256 + agp);
        }
#pragma unroll
        for (int mt = 0; mt < 4; ++mt)
#pragma unroll
            for (int nt = 0; nt < 2; ++nt)
                acc[mt][nt] = __builtin_amdgcn_mfma_f32_16x16x32_bf16(
                    af[mt], bfr[nt], acc[mt][nt], 0, 0, 0);
#pragma unroll
        for (int x = 0; x < 4; ++x) af[x] = anx[x];
#pragma unroll
        for (int x = 0; x < 2; ++x) bfr[x] = bnx[x];
    }

    if (!LAST) __syncthreads();   // all K-loop reads of P done before overwrite

    // ---- epilogue: bias + GELU; act -> P (swizzled) + sharded stats,
    //      or final layer -> global f32 out ----
    float s1[2] = {0.f, 0.f};
    float s2[2] = {0.f, 0.f};
#pragma unroll
    for (int mt = 0; mt < 4; ++mt) {
#pragma unroll
        for (int nt = 0; nt < 2; ++nt) {
            const int col = wave * 32 + nt * 16 + l15;       // C/D col=lane&15
#pragma unroll
            for (int i = 0; i < 4; ++i) {
                const int r = mt * 16 + quad * 4 + i;        // C/D row=quad*4+reg
                float y = gelu_fast(acc[mt][nt][i] + bias_v[nt]);
                if (LAST) {
                    p.out[(size_t)(row0 + r) * DDIM + col] = y;
                } else {
                    const int g = col >> 3;
                    P[r * 256 + ((g ^ (r & 7)) << 3) + (col & 7)] = f2bf(y);
                    s1[nt] += y; s2[nt] += y * y;
                }
            }
        }
    }
    if (!LAST) {
#pragma unroll
        for (int nt = 0; nt < 2; ++nt) {   // reduce the 4 quads (same column)
            s1[nt] += __shfl_xor(s1[nt], 16); s1[nt] += __shfl_xor(s1[nt], 32);
            s2[nt] += __shfl_xor(s2[nt], 16); s2[nt] += __shfl_xor(s2[nt], 32);
        }
        float* sb = statShards + (blk & 7) * 512;            // 8-way shard
        if (quad == 0) {
#pragma unroll
            for (int nt = 0; nt < 2; ++nt) {
                const int col = wave * 32 + nt * 16 + l15;
                atomicAdd(&sb[col],       s1[nt]);
                atomicAdd(&sb[256 + col], s2[nt]);
            }
        }
    }
}

// ---------------------------------------------------------------------------
// Fused kernel: L1..L4, atomic-barrier separated. grid 512 x 512thr, 34KB
// static LDS, launch_bounds(512,4) -> VGPR<=128 -> 2 blocks/CU resident.
// ---------------------------------------------------------------------------
__global__ __launch_bounds__(512, 4) void fused_enc(Params p)
{
    __shared__ alignas(16) unsigned short P[64 * 256];   // 32 KB panel
    __shared__ float sc[256], sh[256];                   // 2 KB

    layer_step<1, 0, 0>(P, sc, sh, p, p.Wt,          p.b[0],
                        nullptr,         nullptr, nullptr, p.stats);
    grid_barrier(p.barrier, 0);
    layer_step<0, 1, 0>(P, sc, sh, p, p.Wt + 65536,  p.b[1],
                        p.stats,         p.g[0],  p.be[0], p.stats + 4096);
    grid_barrier(p.barrier, 1);
    layer_step<0, 1, 0>(P, sc, sh, p, p.Wt + 131072, p.b[2],
                        p.stats + 4096,  p.g[1],  p.be[1], p.stats + 8192);
    grid_barrier(p.barrier, 2);
    layer_step<0, 1, 1>(P, sc, sh, p, p.Wt + 196608, p.b[3],
                        p.stats + 8192,  p.g[2],  p.be[2], nullptr);
}

// ---------------------------------------------------------------------------
extern "C" void kernel_launch(void* const* d_in, const int* in_sizes, int n_in,
                              void* d_out, int out_size, void* d_ws, size_t ws_size,
                              hipStream_t stream)
{
    const float* W1 = (const float*)d_in[2];
    const float* W2 = (const float*)d_in[4];
    const float* W3 = (const float*)d_in[6];
    const float* W4 = (const float*)d_in[8];

    Params pp;
    pp.ids   = (const int*)  d_in[0];
    pp.table = (const float*)d_in[1];
    pp.b[0] = (const float*)d_in[3];
    pp.b[1] = (const float*)d_in[5];
    pp.b[2] = (const float*)d_in[7];
    pp.b[3] = (const float*)d_in[9];
    pp.g[0] = (const float*)d_in[10]; pp.be[0] = (const float*)d_in[11];
    pp.g[1] = (const float*)d_in[12]; pp.be[1] = (const float*)d_in[13];
    pp.g[2] = (const float*)d_in[14]; pp.be[2] = (const float*)d_in[15];

    unsigned char* ws = (unsigned char*)d_ws;
    unsigned short* Wt = (unsigned short*)ws;             // 512 KiB
    float* stats       = (float*)(ws + (size_t)524288);   // 48 KiB
    unsigned int* bar  = (unsigned int*)(ws + (size_t)589824); // 2 KiB

    pp.Wt      = Wt;
    pp.stats   = stats;
    pp.barrier = bar;
    pp.out     = (float*)d_out;

    prep_kernel<<<1024, 256, 0, stream>>>(W1, W2, W3, W4, Wt, stats, bar);
    fused_enc<<<dim3(NBLK), dim3(512), 0, stream>>>(pp);
}

// Round 7
// 167.397 us; speedup vs baseline: 3.1300x; 1.0459x over previous
//
#include <hip/hip_runtime.h>
#include <math.h>

// ---------------------------------------------------------------------------
// StatePerturbationEncoder, R15: R14 + tree-arrival barrier + LDS-tiled prep.
//  R14 post-mortem: decontended flag polling worked (107->77.6us). Remaining:
//  (1) 512 same-line fetch_adds per barrier serialize at the coherence point
//      (~5-15us/barrier). R15: 8 group counters (64 arrivals each, separate
//      64B lines, parallel) -> root (8 RMWs) -> flag. Serial chain ~64 RMWs.
//  (2) dur-fused gap ~97us; prep (1024 tiny blocks, scattered per-element
//      transpose) estimated 25-30us of it. R15: 64-block LDS-tiled
//      transpose, coalesced float4 reads + 32B-chunk writes (~3-5us).
//  fused_enc layer math byte-identical to the passing R14 (absmax 0.0234).
// ---------------------------------------------------------------------------

typedef __attribute__((ext_vector_type(8))) short short8;   // 8 x bf16
typedef __attribute__((ext_vector_type(4))) float floatx4;  // MFMA acc

#define DDIM 256
#define NBLK 512

struct Params {
    const int* ids;
    const float* table;
    const float* b[4];
    const float* g[3];
    const float* be[3];
    const unsigned short* Wt;  // ws: 4 * 65536 bf16 (filled by prep)
    float* stats;              // ws: 12288 f32 (3 layers x 8 shards x 512)
    unsigned int* barrier;     // ws: 4KB region (3 phases x 256 uints used)
    float* out;                // d_out f32
};

__device__ __forceinline__ unsigned short f2bf(float f) {
    union { float f; unsigned int u; } v; v.f = f;
    unsigned int r = v.u + 0x7fffu + ((v.u >> 16) & 1u);   // RNE
    return (unsigned short)(r >> 16);
}
__device__ __forceinline__ float bf2f(unsigned short u) {
    union { unsigned int i; float f; } v; v.i = ((unsigned int)u) << 16;
    return v.f;
}
__device__ __forceinline__ float gelu_fast(float x) {
    // tanh-approx GELU, branchless (validated: absmax 0.023 vs 0.076 thr)
    float z = 0.7978845608f * (x + 0.044715f * x * x * x);
    float e = __expf(2.0f * z);
    float th = 1.0f - 2.0f * __builtin_amdgcn_rcpf(1.0f + e);
    return 0.5f * x * (1.0f + th);
}

// ---------------------------------------------------------------------------
// K0: LDS-tiled transpose+cast W -> Wt (bf16 [n][k]); zero stats + barrier.
// 64 blocks: block b -> W[b>>4], 64x64 tile (b&15). Coalesced float4 reads,
// LDS [64][68] staging (2-way-free padding), 32B-chunk transposed writes.
// ---------------------------------------------------------------------------
__global__ __launch_bounds__(256) void prep_kernel(
    const float* __restrict__ W0, const float* __restrict__ W1,
    const float* __restrict__ W2, const float* __restrict__ W3,
    unsigned short* __restrict__ Wt, float* __restrict__ stats,
    unsigned int* __restrict__ barrier)
{
    __shared__ unsigned short T[64][68];
    const int t = threadIdx.x, b = blockIdx.x;     // 64 blocks x 256 thr
    const int j  = b >> 4;
    const int kr = ((b >> 2) & 3) * 64;            // k (row of W) base
    const int nc = (b & 3) * 64;                   // n (col of W) base
    const float* W = (j == 0) ? W0 : (j == 1) ? W1 : (j == 2) ? W2 : W3;

    {   // load: thread t -> k = kr+(t>>2), cols nc+(t&3)*16 .. +15
        const int k = t >> 2, c0 = (t & 3) * 16;
        const float* src = W + (size_t)(kr + k) * DDIM + nc + c0;
#pragma unroll
        for (int i = 0; i < 4; ++i) {
            float4 v = *(const float4*)(src + i * 4);
            T[k][c0 + i * 4 + 0] = f2bf(v.x);
            T[k][c0 + i * 4 + 1] = f2bf(v.y);
            T[k][c0 + i * 4 + 2] = f2bf(v.z);
            T[k][c0 + i * 4 + 3] = f2bf(v.w);
        }
    }
    __syncthreads();
    {   // store transposed: thread t -> n = nc+(t>>2), k chunk kr+(t&3)*16..+15
        const int n = t >> 2, kc = (t & 3) * 16;
        union { unsigned short u[16]; uint4 v[2]; } o;
#pragma unroll
        for (int i = 0; i < 16; ++i) o.u[i] = T[kc + i][n];
        uint4* dst = (uint4*)(Wt + ((size_t)j << 16)
                              + (size_t)(nc + n) * DDIM + kr + kc);
        dst[0] = o.v[0]; dst[1] = o.v[1];
    }
    // zero stat shards (48 blocks x 256 f32 = 12288) + barrier region (4KB)
    if (b < 48)       stats[b * 256 + t] = 0.f;
    else if (b < 52)  barrier[(b - 48) * 256 + t] = 0u;
}

// ---------------------------------------------------------------------------
// Grid barrier, tree-arrival (R15): per phase, 8 group counters on separate
// 64B lines (64 arrivals each, RMWs parallel across lines) -> root (8 RMWs)
// -> flag on its own line. Pollers read only the flag (R14-proven). No L2
// wb/inv anywhere. Bounded spin: deadlock -> wrong answer, never a hang.
// Phase layout (256 uints): grp g at [g*16], root at [128], flag at [192].
// ---------------------------------------------------------------------------
__device__ __forceinline__ void grid_barrier(unsigned int* base, int phase)
{
    unsigned int* ph = base + phase * 256;
    __syncthreads();   // s_waitcnt vmcnt(0) lgkmcnt(0) + s_barrier (all waves)
    if (threadIdx.x == 0) {
        asm volatile("s_waitcnt vmcnt(0)" ::: "memory");
        unsigned int* gc   = ph + (blockIdx.x >> 6) * 16;   // 8 groups x 64
        unsigned int* root = ph + 128;
        unsigned int* flag = ph + 192;
        bool done = false;
        unsigned int old = __hip_atomic_fetch_add(gc, 1u, __ATOMIC_RELAXED,
                                                  __HIP_MEMORY_SCOPE_AGENT);
        if (old == 63u) {
            unsigned int r = __hip_atomic_fetch_add(root, 1u, __ATOMIC_RELAXED,
                                                    __HIP_MEMORY_SCOPE_AGENT);
            if (r == 7u) {
                __hip_atomic_store(flag, 1u, __ATOMIC_RELAXED,
                                   __HIP_MEMORY_SCOPE_AGENT);
                done = true;
            }
        }
        if (!done) {
            int cap = 2000000;
            while (!__hip_atomic_load(flag, __ATOMIC_RELAXED,
                                      __HIP_MEMORY_SCOPE_AGENT)) {
                __builtin_amdgcn_s_sleep(8);
                if (--cap == 0) break;
            }
        }
    }
    __syncthreads();
}

// ---------------------------------------------------------------------------
// One layer, 8-wave version (R13/R14-proven). Block tile 64 rows x 256 cols;
// wave wn owns cols wn*32..+31 (acc 4x2 of 16x16x32 MFMAs).
// P layout: row r, granule g (8 bf16) at slot g^(r&7) (conflict-free).
// ---------------------------------------------------------------------------
template<int GATHER, int AFFINE, int LAST>
__device__ __forceinline__ void layer_step(
    unsigned short* P, float* sc, float* sh,
    const Params& p,
    const unsigned short* Wt, const float* bias,
    const float* statsIn, const float* gma, const float* bta,
    float* statShards)
{
    const int tid  = threadIdx.x;          // 0..511
    const int blk  = blockIdx.x;
    const int wave = tid >> 6;             // 0..7
    const int lane = tid & 63;
    const int quad = lane >> 4;
    const int l15  = lane & 15;
    const int row0 = blk * 64;

    if (AFFINE) {
        // threads 0..255 -> column t: finalize BN stats of prev layer.
        // AGENT-scope (sc1) loads read at the coherence point (XCD-safe).
        if (tid < 256) {
            float sum = 0.f, sq = 0.f;
#pragma unroll
            for (int s = 0; s < 8; ++s) {
                sum += __hip_atomic_load(&statsIn[s * 512 + tid],
                                         __ATOMIC_RELAXED, __HIP_MEMORY_SCOPE_AGENT);
                sq  += __hip_atomic_load(&statsIn[s * 512 + 256 + tid],
                                         __ATOMIC_RELAXED, __HIP_MEMORY_SCOPE_AGENT);
            }
            const float mu  = sum * (1.f / 32768.f);
            const float var = sq * (1.f / 32768.f) - mu * mu;
            const float scl = rsqrtf(var + 1e-5f) * gma[tid];
            sc[tid] = scl;
            sh[tid] = bta[tid] - mu * scl;
        }
        __syncthreads();   // sc/sh visible before staging uses them
    }

    // ---- stage A panel (thread t: row t>>3, granules (t&7)*4 .. +3) ----
    {
        const int r     = tid >> 3;
        const int gbase = (tid & 7) * 4;
        if (GATHER) {
            const int src = p.ids[row0 + r];
            const float* tp = p.table + (size_t)src * DDIM + gbase * 8;
#pragma unroll
            for (int j = 0; j < 4; ++j) {
                float4 v0 = *(const float4*)(tp + j * 8);
                float4 v1 = *(const float4*)(tp + j * 8 + 4);
                union { unsigned short u[8]; uint4 v; } o;
                o.u[0]=f2bf(v0.x); o.u[1]=f2bf(v0.y); o.u[2]=f2bf(v0.z); o.u[3]=f2bf(v0.w);
                o.u[4]=f2bf(v1.x); o.u[5]=f2bf(v1.y); o.u[6]=f2bf(v1.z); o.u[7]=f2bf(v1.w);
                const int g = gbase + j;
                *(uint4*)(P + r * 256 + ((g ^ (r & 7)) << 3)) = o.v;
            }
        } else {
            // in-place BN-affine restage. Thread enumerates its own DATA
            // granules g; slot map g->g^(r&7) is a bijection per row, so
            // slots are touched by exactly one thread (read-mod-write safe).
#pragma unroll
            for (int j = 0; j < 4; ++j) {
                const int g = gbase + j;
                unsigned short* slot = P + r * 256 + ((g ^ (r & 7)) << 3);
                union { unsigned short u[8]; uint4 v; } o;
                o.v = *(const uint4*)slot;
#pragma unroll
                for (int e = 0; e < 8; ++e) {
                    const int c = g * 8 + e;
                    o.u[e] = f2bf(fmaf(bf2f(o.u[e]), sc[c], sh[c]));
                }
                *(uint4*)slot = o.v;
            }
        }
    }

    float bias_v[2];
#pragma unroll
    for (int nt = 0; nt < 2; ++nt)
        bias_v[nt] = bias[wave * 32 + nt * 16 + l15];

    floatx4 acc[4][2];
#pragma unroll
    for (int i = 0; i < 4; ++i)
#pragma unroll
        for (int j = 0; j < 2; ++j)
            acc[i][j] = floatx4{0.f, 0.f, 0.f, 0.f};

    __syncthreads();   // A panel visible to all waves

    // ---- K loop: manual 1-deep pipeline; B from global (L2-hot), A LDS ----
    const unsigned short* wb = Wt + (size_t)(wave * 32 + l15) * DDIM + quad * 8;
    short8 bfr[2], bnx[2], af[4], anx[4];
    {
        const int agp = (quad ^ (l15 & 7)) * 8;               // kk = 0
#pragma unroll
        for (int nt = 0; nt < 2; ++nt)
            bfr[nt] = *(const short8*)(wb + (size_t)(nt * 16) * DDIM);
#pragma unroll
        for (int mt = 0; mt < 4; ++mt)
            af[mt] = *(const short8*)(P + (mt * 16 + l15) * 256 + agp);
    }
#pragma unroll
    for (int kk = 0; kk < 8; ++kk) {
        if (kk < 7) {
            const int agp = (((kk + 1) * 4 + quad) ^ (l15 & 7)) * 8;
#pragma unroll
            for (int nt = 0; nt < 2; ++nt)
                bnx[nt] = *(const short8*)(wb + (size_t)(nt * 16) * DDIM
                                           + (kk + 1) * 32);
#pragma unroll
            for (int mt = 0; mt < 4; ++mt)
                anx[mt] = *(const short8*)(P + (mt * 16 + l15) * 256 + agp);
        }
#pragma unroll
        for (int mt = 0; mt < 4; ++mt)
#pragma unroll
            for (int nt = 0; nt < 2; ++nt)
                acc[mt][nt] = __builtin_amdgcn_mfma_f32_16x16x32_bf16(
                    af[mt], bfr[nt], acc[mt][nt], 0, 0, 0);
#pragma unroll
        for (int x = 0; x < 4; ++x) af[x] = anx[x];
#pragma unroll
        for (int x = 0; x < 2; ++x) bfr[x] = bnx[x];
    }

    if (!LAST) __syncthreads();   // all K-loop reads of P done before overwrite

    // ---- epilogue: bias + GELU; act -> P (swizzled) + sharded stats,
    //      or final layer -> global f32 out ----
    float s1[2] = {0.f, 0.f};
    float s2[2] = {0.f, 0.f};
#pragma unroll
    for (int mt = 0; mt < 4; ++mt) {
#pragma unroll
        for (int nt = 0; nt < 2; ++nt) {
            const int col = wave * 32 + nt * 16 + l15;       // C/D col=lane&15
#pragma unroll
            for (int i = 0; i < 4; ++i) {
                const int r = mt * 16 + quad * 4 + i;        // C/D row=quad*4+reg
                float y = gelu_fast(acc[mt][nt][i] + bias_v[nt]);
                if (LAST) {
                    p.out[(size_t)(row0 + r) * DDIM + col] = y;
                } else {
                    const int g = col >> 3;
                    P[r * 256 + ((g ^ (r & 7)) << 3) + (col & 7)] = f2bf(y);
                    s1[nt] += y; s2[nt] += y * y;
                }
            }
        }
    }
    if (!LAST) {
#pragma unroll
        for (int nt = 0; nt < 2; ++nt) {   // reduce the 4 quads (same column)
            s1[nt] += __shfl_xor(s1[nt], 16); s1[nt] += __shfl_xor(s1[nt], 32);
            s2[nt] += __shfl_xor(s2[nt], 16); s2[nt] += __shfl_xor(s2[nt], 32);
        }
        float* sb = statShards + (blk & 7) * 512;            // 8-way shard
        if (quad == 0) {
#pragma unroll
            for (int nt = 0; nt < 2; ++nt) {
                const int col = wave * 32 + nt * 16 + l15;
                atomicAdd(&sb[col],       s1[nt]);
                atomicAdd(&sb[256 + col], s2[nt]);
            }
        }
    }
}

// ---------------------------------------------------------------------------
// Fused kernel: L1..L4, tree-barrier separated. grid 512 x 512thr, 34KB
// static LDS, launch_bounds(512,4) -> VGPR<=128 -> 2 blocks/CU resident.
// ---------------------------------------------------------------------------
__global__ __launch_bounds__(512, 4) void fused_enc(Params p)
{
    __shared__ alignas(16) unsigned short P[64 * 256];   // 32 KB panel
    __shared__ float sc[256], sh[256];                   // 2 KB

    layer_step<1, 0, 0>(P, sc, sh, p, p.Wt,          p.b[0],
                        nullptr,         nullptr, nullptr, p.stats);
    grid_barrier(p.barrier, 0);
    layer_step<0, 1, 0>(P, sc, sh, p, p.Wt + 65536,  p.b[1],
                        p.stats,         p.g[0],  p.be[0], p.stats + 4096);
    grid_barrier(p.barrier, 1);
    layer_step<0, 1, 0>(P, sc, sh, p, p.Wt + 131072, p.b[2],
                        p.stats + 4096,  p.g[1],  p.be[1], p.stats + 8192);
    grid_barrier(p.barrier, 2);
    layer_step<0, 1, 1>(P, sc, sh, p, p.Wt + 196608, p.b[3],
                        p.stats + 8192,  p.g[2],  p.be[2], nullptr);
}

// ---------------------------------------------------------------------------
extern "C" void kernel_launch(void* const* d_in, const int* in_sizes, int n_in,
                              void* d_out, int out_size, void* d_ws, size_t ws_size,
                              hipStream_t stream)
{
    const float* W1 = (const float*)d_in[2];
    const float* W2 = (const float*)d_in[4];
    const float* W3 = (const float*)d_in[6];
    const float* W4 = (const float*)d_in[8];

    Params pp;
    pp.ids   = (const int*)  d_in[0];
    pp.table = (const float*)d_in[1];
    pp.b[0] = (const float*)d_in[3];
    pp.b[1] = (const float*)d_in[5];
    pp.b[2] = (const float*)d_in[7];
    pp.b[3] = (const float*)d_in[9];
    pp.g[0] = (const float*)d_in[10]; pp.be[0] = (const float*)d_in[11];
    pp.g[1] = (const float*)d_in[12]; pp.be[1] = (const float*)d_in[13];
    pp.g[2] = (const float*)d_in[14]; pp.be[2] = (const float*)d_in[15];

    unsigned char* ws = (unsigned char*)d_ws;
    unsigned short* Wt = (unsigned short*)ws;             // 512 KiB
    float* stats       = (float*)(ws + (size_t)524288);   // 48 KiB
    unsigned int* bar  = (unsigned int*)(ws + (size_t)589824); // 4 KiB

    pp.Wt      = Wt;
    pp.stats   = stats;
    pp.barrier = bar;
    pp.out     = (float*)d_out;

    prep_kernel<<<64, 256, 0, stream>>>(W1, W2, W3, W4, Wt, stats, bar);
    fused_enc<<<dim3(NBLK), dim3(512), 0, stream>>>(pp);
}